// Round 1
// baseline (454.628 us; speedup 1.0000x reference)
//
#include <hip/hip_runtime.h>

#define NPOINTS 500000
#define RESOLUTION 128.0f
#define IDX_MASK 0x7FFFFu    // INDEX_TABLE_SIZE-1  (2^19)
#define FEAT_MASK 0xFFFFFu   // FEATURE_TABLE_SIZE-1 (2^20)
#define P1 2654435761u
#define P2 805459861u

// One lane per (point, corner). 8 consecutive lanes = 8 corners of one point.
__global__ __launch_bounds__(256) void hashgrid_fwd(
    const float* __restrict__ x,
    const float* __restrict__ feature_table,
    const float* __restrict__ index_table,
    float* __restrict__ out)
{
    int tid = blockIdx.x * blockDim.x + threadIdx.x;
    int p = tid >> 3;
    int corner = tid & 7;
    if (p >= NPOINTS) return;   // grid divides exactly; kept for safety

    // --- point coords (8 lanes share address -> L1 broadcast) ---
    float xs0 = x[p * 3 + 0] * RESOLUTION;
    float xs1 = x[p * 3 + 1] * RESOLUTION;
    float xs2 = x[p * 3 + 2] * RESOLUTION;
    int i0 = (int)xs0, i1 = (int)xs1, i2 = (int)xs2;
    float f0 = xs0 - (float)i0, f1 = xs1 - (float)i1, f2 = xs2 - (float)i2;

    // --- corner offset bits: BIN_MASK true (bit==0) -> ind=xi, w=1-xf ---
    unsigned b0 = corner & 1u, b1 = (corner >> 1) & 1u, b2 = (corner >> 2) & 1u;
    unsigned ind0 = (unsigned)i0 + b0;
    unsigned ind1 = (unsigned)i1 + b1;
    unsigned ind2 = (unsigned)i2 + b2;
    float w0 = b0 ? f0 : 1.0f - f0;
    float w1 = b1 ? f1 : 1.0f - f1;
    float w2 = b2 ? f2 : 1.0f - f2;
    float w = w0 * w1 * w2;

    // --- hash (exact uint32 arithmetic) ---
    unsigned h = (ind0 * 1u) ^ (ind1 * P1) ^ (ind2 * P2);
    h &= IDX_MASK;

    // --- index_table[h][0..7] : 32B row, two float4 loads ---
    const float4* itp = (const float4*)(index_table + (size_t)h * 8u);
    float4 iw0 = itp[0];
    float4 iw1 = itp[1];
    float e0 = iw0.x, e1 = iw0.y, e2 = iw0.z, e3 = iw0.w;
    float e4 = iw1.x, e5 = iw1.y, e6 = iw1.z, e7 = iw1.w;

    // --- softmax (max-subtracted, denominator folded into final scale) ---
    float mx = fmaxf(fmaxf(fmaxf(e0, e1), fmaxf(e2, e3)),
                     fmaxf(fmaxf(e4, e5), fmaxf(e6, e7)));
    e0 = __expf(e0 - mx); e1 = __expf(e1 - mx);
    e2 = __expf(e2 - mx); e3 = __expf(e3 - mx);
    e4 = __expf(e4 - mx); e5 = __expf(e5 - mx);
    e6 = __expf(e6 - mx); e7 = __expf(e7 - mx);
    float s = ((e0 + e1) + (e2 + e3)) + ((e4 + e5) + (e6 + e7));

    // --- 8 feature gathers; addresses depend only on h -> all issue early ---
    unsigned hp2 = h * P2;
    const float4* ftp = (const float4*)feature_table;
    float ax = 0.f, ay = 0.f, az = 0.f, aw = 0.f;
    float ej[8] = {e0, e1, e2, e3, e4, e5, e6, e7};
#pragma unroll
    for (unsigned j = 0; j < 8; ++j) {
        unsigned a = ((j * P1) ^ hp2) & FEAT_MASK;
        float4 ft = ftp[a];
        ax = fmaf(ft.x, ej[j], ax);
        ay = fmaf(ft.y, ej[j], ay);
        az = fmaf(ft.z, ej[j], az);
        aw = fmaf(ft.w, ej[j], aw);
    }

    float scale = w / s;       // softmax denom + trilinear weight in one mult
    ax *= scale; ay *= scale; az *= scale; aw *= scale;

    // --- sum the 8 corners (8 adjacent lanes) via butterfly shuffles ---
#pragma unroll
    for (int m = 1; m < 8; m <<= 1) {
        ax += __shfl_xor(ax, m);
        ay += __shfl_xor(ay, m);
        az += __shfl_xor(az, m);
        aw += __shfl_xor(aw, m);
    }

    if (corner == 0) {
        ((float4*)out)[p] = make_float4(ax, ay, az, aw);
    }
}

extern "C" void kernel_launch(void* const* d_in, const int* in_sizes, int n_in,
                              void* d_out, int out_size, void* d_ws, size_t ws_size,
                              hipStream_t stream) {
    const float* x  = (const float*)d_in[0];
    const float* ft = (const float*)d_in[1];
    const float* it = (const float*)d_in[2];
    float* out = (float*)d_out;

    const int total = NPOINTS * 8;          // 4,000,000 lanes
    const int block = 256;
    const int grid = (total + block - 1) / block;  // 15625
    hipLaunchKernelGGL(hashgrid_fwd, dim3(grid), dim3(block), 0, stream,
                       x, ft, it, out);
}

// Round 3
// 92.330 us; speedup vs baseline: 4.9239x; 4.9239x over previous
//
#include <hip/hip_runtime.h>

#define NPOINTS 500000
#define RESOLUTION 128.0f
#define IDX_SIZE 524288u     // INDEX_TABLE_SIZE (2^19)
#define IDX_MASK 0x7FFFFu
#define FEAT_MASK 0xFFFFFu   // FEATURE_TABLE_SIZE-1 (2^20)
#define P1 2654435761u
#define P2 805459861u

// ---------------- Phase 1: F[h] = sum_j feature_table[a(h,j)] * softmax_j(index_table[h])
__global__ __launch_bounds__(256) void build_F(
    const float* __restrict__ feature_table,
    const float* __restrict__ index_table,
    float4* __restrict__ F)
{
    unsigned h = blockIdx.x * blockDim.x + threadIdx.x;   // grid covers exactly 2^19

    const float4* itp = (const float4*)(index_table + (size_t)h * 8u);
    float4 iw0 = itp[0];
    float4 iw1 = itp[1];
    float e0 = iw0.x, e1 = iw0.y, e2 = iw0.z, e3 = iw0.w;
    float e4 = iw1.x, e5 = iw1.y, e6 = iw1.z, e7 = iw1.w;

    float mx = fmaxf(fmaxf(fmaxf(e0, e1), fmaxf(e2, e3)),
                     fmaxf(fmaxf(e4, e5), fmaxf(e6, e7)));
    e0 = __expf(e0 - mx); e1 = __expf(e1 - mx);
    e2 = __expf(e2 - mx); e3 = __expf(e3 - mx);
    e4 = __expf(e4 - mx); e5 = __expf(e5 - mx);
    e6 = __expf(e6 - mx); e7 = __expf(e7 - mx);
    float s = ((e0 + e1) + (e2 + e3)) + ((e4 + e5) + (e6 + e7));

    unsigned hp2 = h * P2;
    const float4* ftp = (const float4*)feature_table;
    float ej[8] = {e0, e1, e2, e3, e4, e5, e6, e7};
    float ax = 0.f, ay = 0.f, az = 0.f, aw = 0.f;
#pragma unroll
    for (unsigned j = 0; j < 8; ++j) {
        unsigned a = ((j * P1) ^ hp2) & FEAT_MASK;
        float4 ft = ftp[a];
        ax = fmaf(ft.x, ej[j], ax);
        ay = fmaf(ft.y, ej[j], ay);
        az = fmaf(ft.z, ej[j], az);
        aw = fmaf(ft.w, ej[j], aw);
    }
    float inv = 1.0f / s;                 // fold softmax denominator here
    F[h] = make_float4(ax * inv, ay * inv, az * inv, aw * inv);
}

// ---------------- Phase 2: out[p] = sum_c F[h(p,c)] * w(p,c)
__global__ __launch_bounds__(256) void interp(
    const float* __restrict__ x,
    const float4* __restrict__ F,
    float4* __restrict__ out)
{
    int p = blockIdx.x * blockDim.x + threadIdx.x;
    if (p >= NPOINTS) return;

    float xs0 = x[p * 3 + 0] * RESOLUTION;
    float xs1 = x[p * 3 + 1] * RESOLUTION;
    float xs2 = x[p * 3 + 2] * RESOLUTION;
    int i0 = (int)xs0, i1 = (int)xs1, i2 = (int)xs2;
    float f0 = xs0 - (float)i0, f1 = xs1 - (float)i1, f2 = xs2 - (float)i2;
    float g0 = 1.0f - f0, g1 = 1.0f - f1, g2 = 1.0f - f2;

    unsigned u0 = (unsigned)i0;
    unsigned m1a = (unsigned)i1 * P1, m1b = ((unsigned)i1 + 1u) * P1;
    unsigned m2a = (unsigned)i2 * P2, m2b = ((unsigned)i2 + 1u) * P2;

    float ax = 0.f, ay = 0.f, az = 0.f, aw = 0.f;
#pragma unroll
    for (int c = 0; c < 8; ++c) {
        unsigned b0 = c & 1, b1 = (c >> 1) & 1, b2 = (c >> 2) & 1;
        unsigned h = ((u0 + b0) ^ (b1 ? m1b : m1a) ^ (b2 ? m2b : m2a)) & IDX_MASK;
        float w = (b0 ? f0 : g0) * (b1 ? f1 : g1) * (b2 ? f2 : g2);
        float4 f = F[h];
        ax = fmaf(f.x, w, ax);
        ay = fmaf(f.y, w, ay);
        az = fmaf(f.z, w, az);
        aw = fmaf(f.w, w, aw);
    }
    out[p] = make_float4(ax, ay, az, aw);
}

// ---------------- Fallback (proven R1 kernel) if ws is too small ----------------
__global__ __launch_bounds__(256) void hashgrid_fwd(
    const float* __restrict__ x,
    const float* __restrict__ feature_table,
    const float* __restrict__ index_table,
    float* __restrict__ out)
{
    int tid = blockIdx.x * blockDim.x + threadIdx.x;
    int p = tid >> 3;
    int corner = tid & 7;
    if (p >= NPOINTS) return;

    float xs0 = x[p * 3 + 0] * RESOLUTION;
    float xs1 = x[p * 3 + 1] * RESOLUTION;
    float xs2 = x[p * 3 + 2] * RESOLUTION;
    int i0 = (int)xs0, i1 = (int)xs1, i2 = (int)xs2;
    float f0 = xs0 - (float)i0, f1 = xs1 - (float)i1, f2 = xs2 - (float)i2;

    unsigned b0 = corner & 1u, b1 = (corner >> 1) & 1u, b2 = (corner >> 2) & 1u;
    unsigned ind0 = (unsigned)i0 + b0;
    unsigned ind1 = (unsigned)i1 + b1;
    unsigned ind2 = (unsigned)i2 + b2;
    float w0 = b0 ? f0 : 1.0f - f0;
    float w1 = b1 ? f1 : 1.0f - f1;
    float w2 = b2 ? f2 : 1.0f - f2;
    float w = w0 * w1 * w2;

    unsigned h = (ind0 ^ ind1 * P1 ^ ind2 * P2) & IDX_MASK;

    const float4* itp = (const float4*)(index_table + (size_t)h * 8u);
    float4 iw0 = itp[0];
    float4 iw1 = itp[1];
    float e0 = iw0.x, e1 = iw0.y, e2 = iw0.z, e3 = iw0.w;
    float e4 = iw1.x, e5 = iw1.y, e6 = iw1.z, e7 = iw1.w;

    float mx = fmaxf(fmaxf(fmaxf(e0, e1), fmaxf(e2, e3)),
                     fmaxf(fmaxf(e4, e5), fmaxf(e6, e7)));
    e0 = __expf(e0 - mx); e1 = __expf(e1 - mx);
    e2 = __expf(e2 - mx); e3 = __expf(e3 - mx);
    e4 = __expf(e4 - mx); e5 = __expf(e5 - mx);
    e6 = __expf(e6 - mx); e7 = __expf(e7 - mx);
    float s = ((e0 + e1) + (e2 + e3)) + ((e4 + e5) + (e6 + e7));

    unsigned hp2 = h * P2;
    const float4* ftp = (const float4*)feature_table;
    float ax = 0.f, ay = 0.f, az = 0.f, aw = 0.f;
    float ej[8] = {e0, e1, e2, e3, e4, e5, e6, e7};
#pragma unroll
    for (unsigned j = 0; j < 8; ++j) {
        unsigned a = ((j * P1) ^ hp2) & FEAT_MASK;
        float4 ft = ftp[a];
        ax = fmaf(ft.x, ej[j], ax);
        ay = fmaf(ft.y, ej[j], ay);
        az = fmaf(ft.z, ej[j], az);
        aw = fmaf(ft.w, ej[j], aw);
    }

    float scale = w / s;
    ax *= scale; ay *= scale; az *= scale; aw *= scale;

#pragma unroll
    for (int m = 1; m < 8; m <<= 1) {
        ax += __shfl_xor(ax, m);
        ay += __shfl_xor(ay, m);
        az += __shfl_xor(az, m);
        aw += __shfl_xor(aw, m);
    }
    if (corner == 0) {
        ((float4*)out)[p] = make_float4(ax, ay, az, aw);
    }
}

extern "C" void kernel_launch(void* const* d_in, const int* in_sizes, int n_in,
                              void* d_out, int out_size, void* d_ws, size_t ws_size,
                              hipStream_t stream) {
    const float* x  = (const float*)d_in[0];
    const float* ft = (const float*)d_in[1];
    const float* it = (const float*)d_in[2];

    const size_t F_BYTES = (size_t)IDX_SIZE * 16u;   // 8 MiB

    if (ws_size >= F_BYTES) {
        float4* F = (float4*)d_ws;
        hipLaunchKernelGGL(build_F, dim3(IDX_SIZE / 256), dim3(256), 0, stream,
                           ft, it, F);
        const int grid2 = (NPOINTS + 255) / 256;     // 1954
        hipLaunchKernelGGL(interp, dim3(grid2), dim3(256), 0, stream,
                           x, F, (float4*)d_out);
    } else {
        const int total = NPOINTS * 8;
        hipLaunchKernelGGL(hashgrid_fwd, dim3((total + 255) / 256), dim3(256), 0, stream,
                           x, ft, it, (float*)d_out);
    }
}

// Round 4
// 84.619 us; speedup vs baseline: 5.3726x; 1.0911x over previous
//
#include <hip/hip_runtime.h>

#define NPOINTS 500000
#define RESOLUTION 128.0f
#define IDX_SIZE 524288u     // INDEX_TABLE_SIZE (2^19)
#define IDX_HALF 262144u
#define IDX_MASK 0x7FFFFu
#define FEAT_MASK 0xFFFFFu   // FEATURE_TABLE_SIZE-1 (2^20)
#define P1 2654435761u
#define P2 805459861u

typedef float    f4v __attribute__((ext_vector_type(4)));
typedef unsigned u2v __attribute__((ext_vector_type(2)));

__device__ inline unsigned bf16pack(float a, float b) {
    unsigned ua = __float_as_uint(a); ua = (ua + 0x7FFFu + ((ua >> 16) & 1u)) >> 16;
    unsigned ub = __float_as_uint(b); ub = (ub + 0x7FFFu + ((ub >> 16) & 1u)) >> 16;
    return ua | (ub << 16);
}

// ---------------- Phase 1: F[h] = sum_j ft[a(h,j)] * softmax_j(it[h]), bf16-packed.
// Two h per lane for 20 outstanding vmem ops (16 feature gathers + 4 index loads).
__global__ __launch_bounds__(256) void build_F(
    const float* __restrict__ feature_table,
    const float* __restrict__ index_table,
    u2v* __restrict__ F)
{
    unsigned g = blockIdx.x * blockDim.x + threadIdx.x;   // 0..262143
    unsigned hh[2] = { g, g + IDX_HALF };

    // index rows (coalesced 32B/lane streams, nontemporal: zero reuse)
    f4v iw0[2], iw1[2];
#pragma unroll
    for (int r = 0; r < 2; ++r) {
        const f4v* p = (const f4v*)(index_table + (size_t)hh[r] * 8u);
        iw0[r] = __builtin_nontemporal_load(p);
        iw1[r] = __builtin_nontemporal_load(p + 1);
    }

    // all 16 feature gathers issue up-front (addresses depend only on h)
    f4v fv[2][8];
#pragma unroll
    for (int r = 0; r < 2; ++r) {
        unsigned hp2 = hh[r] * P2;
        const f4v* ftp = (const f4v*)feature_table;
#pragma unroll
        for (unsigned j = 0; j < 8; ++j) {
            unsigned a = ((j * P1) ^ hp2) & FEAT_MASK;
            fv[r][j] = ftp[a];
        }
    }

#pragma unroll
    for (int r = 0; r < 2; ++r) {
        float e[8] = { iw0[r].x, iw0[r].y, iw0[r].z, iw0[r].w,
                       iw1[r].x, iw1[r].y, iw1[r].z, iw1[r].w };
        float mx = fmaxf(fmaxf(fmaxf(e[0], e[1]), fmaxf(e[2], e[3])),
                         fmaxf(fmaxf(e[4], e[5]), fmaxf(e[6], e[7])));
        float s = 0.f;
#pragma unroll
        for (int j = 0; j < 8; ++j) { e[j] = __expf(e[j] - mx); s += e[j]; }

        float ax = 0.f, ay = 0.f, az = 0.f, aw = 0.f;
#pragma unroll
        for (int j = 0; j < 8; ++j) {
            ax = fmaf(fv[r][j].x, e[j], ax);
            ay = fmaf(fv[r][j].y, e[j], ay);
            az = fmaf(fv[r][j].z, e[j], az);
            aw = fmaf(fv[r][j].w, e[j], aw);
        }
        float inv = 1.0f / s;
        ax *= inv; ay *= inv; az *= inv; aw *= inv;

        u2v packed;
        packed.x = bf16pack(ax, ay);
        packed.y = bf16pack(az, aw);
        F[hh[r]] = packed;
    }
}

// ---------------- Phase 2: out[p] = sum_c F[h(p,c)] * w(p,c); F is bf16x4 (4MB, ~L2-resident)
__global__ __launch_bounds__(256) void interp(
    const float* __restrict__ x,
    const u2v* __restrict__ F,
    float4* __restrict__ out)
{
    int p = blockIdx.x * blockDim.x + threadIdx.x;
    if (p >= NPOINTS) return;

    float xs0 = x[p * 3 + 0] * RESOLUTION;
    float xs1 = x[p * 3 + 1] * RESOLUTION;
    float xs2 = x[p * 3 + 2] * RESOLUTION;
    int i0 = (int)xs0, i1 = (int)xs1, i2 = (int)xs2;
    float f0 = xs0 - (float)i0, f1 = xs1 - (float)i1, f2 = xs2 - (float)i2;
    float g0 = 1.0f - f0, g1 = 1.0f - f1, g2 = 1.0f - f2;

    unsigned u0 = (unsigned)i0;
    unsigned m1a = (unsigned)i1 * P1, m1b = ((unsigned)i1 + 1u) * P1;
    unsigned m2a = (unsigned)i2 * P2, m2b = ((unsigned)i2 + 1u) * P2;

    float ax = 0.f, ay = 0.f, az = 0.f, aw = 0.f;
#pragma unroll
    for (int c = 0; c < 8; ++c) {
        unsigned b0 = c & 1, b1 = (c >> 1) & 1, b2 = (c >> 2) & 1;
        unsigned h = ((u0 + b0) ^ (b1 ? m1b : m1a) ^ (b2 ? m2b : m2a)) & IDX_MASK;
        float w = (b0 ? f0 : g0) * (b1 ? f1 : g1) * (b2 ? f2 : g2);
        u2v fv = F[h];
        float fx = __uint_as_float(fv.x << 16);
        float fy = __uint_as_float(fv.x & 0xFFFF0000u);
        float fz = __uint_as_float(fv.y << 16);
        float fw = __uint_as_float(fv.y & 0xFFFF0000u);
        ax = fmaf(fx, w, ax);
        ay = fmaf(fy, w, ay);
        az = fmaf(fz, w, az);
        aw = fmaf(fw, w, aw);
    }
    out[p] = make_float4(ax, ay, az, aw);
}

// ---------------- Fallback (proven R1 kernel) if ws is too small ----------------
__global__ __launch_bounds__(256) void hashgrid_fwd(
    const float* __restrict__ x,
    const float* __restrict__ feature_table,
    const float* __restrict__ index_table,
    float* __restrict__ out)
{
    int tid = blockIdx.x * blockDim.x + threadIdx.x;
    int p = tid >> 3;
    int corner = tid & 7;
    if (p >= NPOINTS) return;

    float xs0 = x[p * 3 + 0] * RESOLUTION;
    float xs1 = x[p * 3 + 1] * RESOLUTION;
    float xs2 = x[p * 3 + 2] * RESOLUTION;
    int i0 = (int)xs0, i1 = (int)xs1, i2 = (int)xs2;
    float f0 = xs0 - (float)i0, f1 = xs1 - (float)i1, f2 = xs2 - (float)i2;

    unsigned b0 = corner & 1u, b1 = (corner >> 1) & 1u, b2 = (corner >> 2) & 1u;
    unsigned ind0 = (unsigned)i0 + b0;
    unsigned ind1 = (unsigned)i1 + b1;
    unsigned ind2 = (unsigned)i2 + b2;
    float w0 = b0 ? f0 : 1.0f - f0;
    float w1 = b1 ? f1 : 1.0f - f1;
    float w2 = b2 ? f2 : 1.0f - f2;
    float w = w0 * w1 * w2;

    unsigned h = (ind0 ^ ind1 * P1 ^ ind2 * P2) & IDX_MASK;

    const float4* itp = (const float4*)(index_table + (size_t)h * 8u);
    float4 iw0 = itp[0];
    float4 iw1 = itp[1];
    float e0 = iw0.x, e1 = iw0.y, e2 = iw0.z, e3 = iw0.w;
    float e4 = iw1.x, e5 = iw1.y, e6 = iw1.z, e7 = iw1.w;

    float mx = fmaxf(fmaxf(fmaxf(e0, e1), fmaxf(e2, e3)),
                     fmaxf(fmaxf(e4, e5), fmaxf(e6, e7)));
    e0 = __expf(e0 - mx); e1 = __expf(e1 - mx);
    e2 = __expf(e2 - mx); e3 = __expf(e3 - mx);
    e4 = __expf(e4 - mx); e5 = __expf(e5 - mx);
    e6 = __expf(e6 - mx); e7 = __expf(e7 - mx);
    float s = ((e0 + e1) + (e2 + e3)) + ((e4 + e5) + (e6 + e7));

    unsigned hp2 = h * P2;
    const float4* ftp = (const float4*)feature_table;
    float ax = 0.f, ay = 0.f, az = 0.f, aw = 0.f;
    float ej[8] = {e0, e1, e2, e3, e4, e5, e6, e7};
#pragma unroll
    for (unsigned j = 0; j < 8; ++j) {
        unsigned a = ((j * P1) ^ hp2) & FEAT_MASK;
        float4 ft = ftp[a];
        ax = fmaf(ft.x, ej[j], ax);
        ay = fmaf(ft.y, ej[j], ay);
        az = fmaf(ft.z, ej[j], az);
        aw = fmaf(ft.w, ej[j], aw);
    }

    float scale = w / s;
    ax *= scale; ay *= scale; az *= scale; aw *= scale;

#pragma unroll
    for (int m = 1; m < 8; m <<= 1) {
        ax += __shfl_xor(ax, m);
        ay += __shfl_xor(ay, m);
        az += __shfl_xor(az, m);
        aw += __shfl_xor(aw, m);
    }
    if (corner == 0) {
        ((float4*)out)[p] = make_float4(ax, ay, az, aw);
    }
}

extern "C" void kernel_launch(void* const* d_in, const int* in_sizes, int n_in,
                              void* d_out, int out_size, void* d_ws, size_t ws_size,
                              hipStream_t stream) {
    const float* x  = (const float*)d_in[0];
    const float* ft = (const float*)d_in[1];
    const float* it = (const float*)d_in[2];

    const size_t F_BYTES = (size_t)IDX_SIZE * 8u;   // 4 MiB (bf16x4 rows)

    if (ws_size >= F_BYTES) {
        u2v* F = (u2v*)d_ws;
        // Phase 1: 262144 lanes, 2 h each
        hipLaunchKernelGGL(build_F, dim3(IDX_HALF / 256), dim3(256), 0, stream,
                           ft, it, F);
        // Phase 2: one lane per point
        const int grid2 = (NPOINTS + 255) / 256;     // 1954
        hipLaunchKernelGGL(interp, dim3(grid2), dim3(256), 0, stream,
                           x, F, (float4*)d_out);
    } else {
        const int total = NPOINTS * 8;
        hipLaunchKernelGGL(hashgrid_fwd, dim3((total + 255) / 256), dim3(256), 0, stream,
                           x, ft, it, (float*)d_out);
    }
}

// Round 5
// 58.116 us; speedup vs baseline: 7.8228x; 1.4561x over previous
//
#include <hip/hip_runtime.h>

#define NPOINTS 500000
#define RESOLUTION 128.0f
#define IDX_SIZE 524288u     // INDEX_TABLE_SIZE (2^19)
#define IDX_MASK 0x7FFFFu
#define FEAT_MASK 0xFFFFFu   // FEATURE_TABLE_SIZE-1 (2^20)
#define P1 2654435761u
#define P2 805459861u

typedef float    f4v __attribute__((ext_vector_type(4)));
typedef unsigned u2v __attribute__((ext_vector_type(2)));

// multiplicative inverse of odd a mod 2^32 (Newton); masked use gives inverse mod 2^20
constexpr unsigned mulinv32(unsigned a) {
    unsigned x = 1u;
    for (int i = 0; i < 6; ++i) x *= 2u - a * x;
    return x;
}
constexpr unsigned P2INV = mulinv32(P2);
static_assert(((P2INV * P2) & FEAT_MASK) == 1u, "bad inverse");

__device__ inline unsigned bf16pack(float a, float b) {
    unsigned ua = __float_as_uint(a); ua = (ua + 0x7FFFu + ((ua >> 16) & 1u)) >> 16;
    unsigned ub = __float_as_uint(b); ub = (ub + 0x7FFFu + ((ub >> 16) & 1u)) >> 16;
    return ua | (ub << 16);
}

// ---------------- Phase 1 (y-order): for y = h*P2 mod 2^20, feature reads are
// ft[y ^ (j*P1 & M)] — 8 XOR-offset streams, each wave covering whole 64B lines.
// Only the 32B index_table row is a random gather; F[h] is a scattered 8B write.
__global__ __launch_bounds__(256) void build_F_y(
    const f4v* __restrict__ ftp,
    const float* __restrict__ index_table,
    u2v* __restrict__ F)
{
    unsigned y = blockIdx.x * blockDim.x + threadIdx.x;   // 0..2^20-1
    unsigned h = (y * P2INV) & FEAT_MASK;                 // h*P2 mod 2^20 == y
    bool valid = h < IDX_SIZE;

    // 8 line-perfect XOR streams (issue regardless of validity: neighbors need the lines)
    f4v fv[8];
#pragma unroll
    for (unsigned j = 0; j < 8; ++j) {
        unsigned cj = (j * P1) & FEAT_MASK;
        fv[j] = ftp[y ^ cj];
    }

    if (!valid) return;

    const f4v* p = (const f4v*)(index_table + (size_t)h * 8u);
    f4v iw0 = p[0];
    f4v iw1 = p[1];
    float e[8] = { iw0.x, iw0.y, iw0.z, iw0.w, iw1.x, iw1.y, iw1.z, iw1.w };

    float mx = fmaxf(fmaxf(fmaxf(e[0], e[1]), fmaxf(e[2], e[3])),
                     fmaxf(fmaxf(e[4], e[5]), fmaxf(e[6], e[7])));
    float s = 0.f;
#pragma unroll
    for (int j = 0; j < 8; ++j) { e[j] = __expf(e[j] - mx); s += e[j]; }

    float ax = 0.f, ay = 0.f, az = 0.f, aw = 0.f;
#pragma unroll
    for (int j = 0; j < 8; ++j) {
        ax = fmaf(fv[j].x, e[j], ax);
        ay = fmaf(fv[j].y, e[j], ay);
        az = fmaf(fv[j].z, e[j], az);
        aw = fmaf(fv[j].w, e[j], aw);
    }
    float inv = 1.0f / s;
    ax *= inv; ay *= inv; az *= inv; aw *= inv;

    u2v packed;
    packed.x = bf16pack(ax, ay);
    packed.y = bf16pack(az, aw);
    F[h] = packed;    // scattered 8B write; disjoint bytes, inter-kernel coherence by runtime
}

// ---------------- Phase 2: out[p] = sum_c F[h(p,c)] * w(p,c); F is bf16x4 (4MB, L2-resident)
__global__ __launch_bounds__(256) void interp(
    const float* __restrict__ x,
    const u2v* __restrict__ F,
    float4* __restrict__ out)
{
    int p = blockIdx.x * blockDim.x + threadIdx.x;
    if (p >= NPOINTS) return;

    float xs0 = x[p * 3 + 0] * RESOLUTION;
    float xs1 = x[p * 3 + 1] * RESOLUTION;
    float xs2 = x[p * 3 + 2] * RESOLUTION;
    int i0 = (int)xs0, i1 = (int)xs1, i2 = (int)xs2;
    float f0 = xs0 - (float)i0, f1 = xs1 - (float)i1, f2 = xs2 - (float)i2;
    float g0 = 1.0f - f0, g1 = 1.0f - f1, g2 = 1.0f - f2;

    unsigned u0 = (unsigned)i0;
    unsigned m1a = (unsigned)i1 * P1, m1b = ((unsigned)i1 + 1u) * P1;
    unsigned m2a = (unsigned)i2 * P2, m2b = ((unsigned)i2 + 1u) * P2;

    float ax = 0.f, ay = 0.f, az = 0.f, aw = 0.f;
#pragma unroll
    for (int c = 0; c < 8; ++c) {
        unsigned b0 = c & 1, b1 = (c >> 1) & 1, b2 = (c >> 2) & 1;
        unsigned h = ((u0 + b0) ^ (b1 ? m1b : m1a) ^ (b2 ? m2b : m2a)) & IDX_MASK;
        float w = (b0 ? f0 : g0) * (b1 ? f1 : g1) * (b2 ? f2 : g2);
        u2v fv = F[h];
        float fx = __uint_as_float(fv.x << 16);
        float fy = __uint_as_float(fv.x & 0xFFFF0000u);
        float fz = __uint_as_float(fv.y << 16);
        float fw = __uint_as_float(fv.y & 0xFFFF0000u);
        ax = fmaf(fx, w, ax);
        ay = fmaf(fy, w, ay);
        az = fmaf(fz, w, az);
        aw = fmaf(fw, w, aw);
    }
    out[p] = make_float4(ax, ay, az, aw);
}

// ---------------- Fallback (proven R1 kernel) if ws is too small ----------------
__global__ __launch_bounds__(256) void hashgrid_fwd(
    const float* __restrict__ x,
    const float* __restrict__ feature_table,
    const float* __restrict__ index_table,
    float* __restrict__ out)
{
    int tid = blockIdx.x * blockDim.x + threadIdx.x;
    int p = tid >> 3;
    int corner = tid & 7;
    if (p >= NPOINTS) return;

    float xs0 = x[p * 3 + 0] * RESOLUTION;
    float xs1 = x[p * 3 + 1] * RESOLUTION;
    float xs2 = x[p * 3 + 2] * RESOLUTION;
    int i0 = (int)xs0, i1 = (int)xs1, i2 = (int)xs2;
    float f0 = xs0 - (float)i0, f1 = xs1 - (float)i1, f2 = xs2 - (float)i2;

    unsigned b0 = corner & 1u, b1 = (corner >> 1) & 1u, b2 = (corner >> 2) & 1u;
    unsigned ind0 = (unsigned)i0 + b0;
    unsigned ind1 = (unsigned)i1 + b1;
    unsigned ind2 = (unsigned)i2 + b2;
    float w0 = b0 ? f0 : 1.0f - f0;
    float w1 = b1 ? f1 : 1.0f - f1;
    float w2 = b2 ? f2 : 1.0f - f2;
    float w = w0 * w1 * w2;

    unsigned h = (ind0 ^ ind1 * P1 ^ ind2 * P2) & IDX_MASK;

    const float4* itp = (const float4*)(index_table + (size_t)h * 8u);
    float4 iw0 = itp[0];
    float4 iw1 = itp[1];
    float e0 = iw0.x, e1 = iw0.y, e2 = iw0.z, e3 = iw0.w;
    float e4 = iw1.x, e5 = iw1.y, e6 = iw1.z, e7 = iw1.w;

    float mx = fmaxf(fmaxf(fmaxf(e0, e1), fmaxf(e2, e3)),
                     fmaxf(fmaxf(e4, e5), fmaxf(e6, e7)));
    e0 = __expf(e0 - mx); e1 = __expf(e1 - mx);
    e2 = __expf(e2 - mx); e3 = __expf(e3 - mx);
    e4 = __expf(e4 - mx); e5 = __expf(e5 - mx);
    e6 = __expf(e6 - mx); e7 = __expf(e7 - mx);
    float s = ((e0 + e1) + (e2 + e3)) + ((e4 + e5) + (e6 + e7));

    unsigned hp2 = h * P2;
    const float4* ftp = (const float4*)feature_table;
    float ax = 0.f, ay = 0.f, az = 0.f, aw = 0.f;
    float ej[8] = {e0, e1, e2, e3, e4, e5, e6, e7};
#pragma unroll
    for (unsigned j = 0; j < 8; ++j) {
        unsigned a = ((j * P1) ^ hp2) & FEAT_MASK;
        float4 ft = ftp[a];
        ax = fmaf(ft.x, ej[j], ax);
        ay = fmaf(ft.y, ej[j], ay);
        az = fmaf(ft.z, ej[j], az);
        aw = fmaf(ft.w, ej[j], aw);
    }

    float scale = w / s;
    ax *= scale; ay *= scale; az *= scale; aw *= scale;

#pragma unroll
    for (int m = 1; m < 8; m <<= 1) {
        ax += __shfl_xor(ax, m);
        ay += __shfl_xor(ay, m);
        az += __shfl_xor(az, m);
        aw += __shfl_xor(aw, m);
    }
    if (corner == 0) {
        ((float4*)out)[p] = make_float4(ax, ay, az, aw);
    }
}

extern "C" void kernel_launch(void* const* d_in, const int* in_sizes, int n_in,
                              void* d_out, int out_size, void* d_ws, size_t ws_size,
                              hipStream_t stream) {
    const float* x  = (const float*)d_in[0];
    const float* ft = (const float*)d_in[1];
    const float* it = (const float*)d_in[2];

    const size_t F_BYTES = (size_t)IDX_SIZE * 8u;   // 4 MiB (bf16x4 rows)

    if (ws_size >= F_BYTES) {
        u2v* F = (u2v*)d_ws;
        // Phase 1: 2^20 y-lanes = 4096 blocks of 256
        hipLaunchKernelGGL(build_F_y, dim3((1u << 20) / 256), dim3(256), 0, stream,
                           (const f4v*)ft, it, F);
        // Phase 2: one lane per point
        const int grid2 = (NPOINTS + 255) / 256;     // 1954
        hipLaunchKernelGGL(interp, dim3(grid2), dim3(256), 0, stream,
                           x, F, (float4*)d_out);
    } else {
        const int total = NPOINTS * 8;
        hipLaunchKernelGGL(hashgrid_fwd, dim3((total + 255) / 256), dim3(256), 0, stream,
                           x, ft, it, (float*)d_out);
    }
}

// Round 6
// 57.720 us; speedup vs baseline: 7.8764x; 1.0069x over previous
//
#include <hip/hip_runtime.h>

#define NPOINTS 500000
#define RESOLUTION 128.0f
#define IDX_SIZE 524288u     // INDEX_TABLE_SIZE (2^19)
#define IDX_MASK 0x7FFFFu
#define FEAT_MASK 0xFFFFFu   // FEATURE_TABLE_SIZE-1 (2^20)
#define P1 2654435761u
#define P2 805459861u

typedef float    f4v __attribute__((ext_vector_type(4)));
typedef unsigned u2v __attribute__((ext_vector_type(2)));

constexpr unsigned mulinv32(unsigned a) {
    unsigned x = 1u;
    for (int i = 0; i < 6; ++i) x *= 2u - a * x;
    return x;
}
constexpr unsigned P2INV = mulinv32(P2);
static_assert(((P2INV * P2) & FEAT_MASK) == 1u, "bad inverse");

__device__ inline unsigned bf16pack(float a, float b) {
    unsigned ua = __float_as_uint(a); ua = (ua + 0x7FFFu + ((ua >> 16) & 1u)) >> 16;
    unsigned ub = __float_as_uint(b); ub = (ub + 0x7FFFu + ((ub >> 16) & 1u)) >> 16;
    return ua | (ub << 16);
}

// ---------------- Phase 1 (y-order): feature reads are 8 XOR-offset line-perfect
// streams. Invalid lanes (h >= 2^19) exit BEFORE issuing loads: their requests
// serve nobody (every valid lane fetches its own row), so masking them halves
// TA request traffic at unchanged byte traffic.
__global__ __launch_bounds__(256) void build_F_y(
    const f4v* __restrict__ ftp,
    const float* __restrict__ index_table,
    u2v* __restrict__ F)
{
    unsigned y = blockIdx.x * blockDim.x + threadIdx.x;   // 0..2^20-1
    unsigned h = (y * P2INV) & FEAT_MASK;                 // h*P2 mod 2^20 == y
    if (h >= IDX_SIZE) return;

    // random 32B index gather first (longest-latency line fetch, start early)
    const f4v* p = (const f4v*)(index_table + (size_t)h * 8u);
    f4v iw0 = p[0];
    f4v iw1 = p[1];

    f4v fv[8];
#pragma unroll
    for (unsigned j = 0; j < 8; ++j) {
        unsigned cj = (j * P1) & FEAT_MASK;
        fv[j] = ftp[y ^ cj];
    }

    float e[8] = { iw0.x, iw0.y, iw0.z, iw0.w, iw1.x, iw1.y, iw1.z, iw1.w };
    float mx = fmaxf(fmaxf(fmaxf(e[0], e[1]), fmaxf(e[2], e[3])),
                     fmaxf(fmaxf(e[4], e[5]), fmaxf(e[6], e[7])));
    float s = 0.f;
#pragma unroll
    for (int j = 0; j < 8; ++j) { e[j] = __expf(e[j] - mx); s += e[j]; }

    float ax = 0.f, ay = 0.f, az = 0.f, aw = 0.f;
#pragma unroll
    for (int j = 0; j < 8; ++j) {
        ax = fmaf(fv[j].x, e[j], ax);
        ay = fmaf(fv[j].y, e[j], ay);
        az = fmaf(fv[j].z, e[j], az);
        aw = fmaf(fv[j].w, e[j], aw);
    }
    float inv = 1.0f / s;
    ax *= inv; ay *= inv; az *= inv; aw *= inv;

    u2v packed;
    packed.x = bf16pack(ax, ay);
    packed.y = bf16pack(az, aw);
    F[h] = packed;
}

// ---------------- Phase 2: two points per lane; all 16 F-gathers hoisted for MLP.
__global__ __launch_bounds__(256) void interp2(
    const float* __restrict__ x,
    const u2v* __restrict__ F,
    float4* __restrict__ out)
{
    int t = blockIdx.x * blockDim.x + threadIdx.x;
    int p0 = t << 1;
    if (p0 >= NPOINTS) return;        // NPOINTS even: p0 and p0+1 both valid

    unsigned hs[16];
    float    ws[16];
#pragma unroll
    for (int r = 0; r < 2; ++r) {
        int p = p0 + r;
        float xs0 = x[p * 3 + 0] * RESOLUTION;
        float xs1 = x[p * 3 + 1] * RESOLUTION;
        float xs2 = x[p * 3 + 2] * RESOLUTION;
        int i0 = (int)xs0, i1 = (int)xs1, i2 = (int)xs2;
        float f0 = xs0 - (float)i0, f1 = xs1 - (float)i1, f2 = xs2 - (float)i2;
        float g0 = 1.0f - f0, g1 = 1.0f - f1, g2 = 1.0f - f2;
        unsigned u0 = (unsigned)i0;
        unsigned m1a = (unsigned)i1 * P1, m1b = ((unsigned)i1 + 1u) * P1;
        unsigned m2a = (unsigned)i2 * P2, m2b = ((unsigned)i2 + 1u) * P2;
#pragma unroll
        for (int c = 0; c < 8; ++c) {
            unsigned b0 = c & 1, b1 = (c >> 1) & 1, b2 = (c >> 2) & 1;
            hs[r * 8 + c] = ((u0 + b0) ^ (b1 ? m1b : m1a) ^ (b2 ? m2b : m2a)) & IDX_MASK;
            ws[r * 8 + c] = (b0 ? f0 : g0) * (b1 ? f1 : g1) * (b2 ? f2 : g2);
        }
    }

    u2v fv[16];
#pragma unroll
    for (int k = 0; k < 16; ++k) fv[k] = F[hs[k]];

#pragma unroll
    for (int r = 0; r < 2; ++r) {
        float ax = 0.f, ay = 0.f, az = 0.f, aw = 0.f;
#pragma unroll
        for (int c = 0; c < 8; ++c) {
            int k = r * 8 + c;
            float fx = __uint_as_float(fv[k].x << 16);
            float fy = __uint_as_float(fv[k].x & 0xFFFF0000u);
            float fz = __uint_as_float(fv[k].y << 16);
            float fw = __uint_as_float(fv[k].y & 0xFFFF0000u);
            ax = fmaf(fx, ws[k], ax);
            ay = fmaf(fy, ws[k], ay);
            az = fmaf(fz, ws[k], az);
            aw = fmaf(fw, ws[k], aw);
        }
        out[p0 + r] = make_float4(ax, ay, az, aw);
    }
}

// ---------------- Fallback (proven R1 kernel) if ws is too small ----------------
__global__ __launch_bounds__(256) void hashgrid_fwd(
    const float* __restrict__ x,
    const float* __restrict__ feature_table,
    const float* __restrict__ index_table,
    float* __restrict__ out)
{
    int tid = blockIdx.x * blockDim.x + threadIdx.x;
    int p = tid >> 3;
    int corner = tid & 7;
    if (p >= NPOINTS) return;

    float xs0 = x[p * 3 + 0] * RESOLUTION;
    float xs1 = x[p * 3 + 1] * RESOLUTION;
    float xs2 = x[p * 3 + 2] * RESOLUTION;
    int i0 = (int)xs0, i1 = (int)xs1, i2 = (int)xs2;
    float f0 = xs0 - (float)i0, f1 = xs1 - (float)i1, f2 = xs2 - (float)i2;

    unsigned b0 = corner & 1u, b1 = (corner >> 1) & 1u, b2 = (corner >> 2) & 1u;
    unsigned ind0 = (unsigned)i0 + b0;
    unsigned ind1 = (unsigned)i1 + b1;
    unsigned ind2 = (unsigned)i2 + b2;
    float w0 = b0 ? f0 : 1.0f - f0;
    float w1 = b1 ? f1 : 1.0f - f1;
    float w2 = b2 ? f2 : 1.0f - f2;
    float w = w0 * w1 * w2;

    unsigned h = (ind0 ^ ind1 * P1 ^ ind2 * P2) & IDX_MASK;

    const float4* itp = (const float4*)(index_table + (size_t)h * 8u);
    float4 iw0 = itp[0];
    float4 iw1 = itp[1];
    float e0 = iw0.x, e1 = iw0.y, e2 = iw0.z, e3 = iw0.w;
    float e4 = iw1.x, e5 = iw1.y, e6 = iw1.z, e7 = iw1.w;

    float mx = fmaxf(fmaxf(fmaxf(e0, e1), fmaxf(e2, e3)),
                     fmaxf(fmaxf(e4, e5), fmaxf(e6, e7)));
    e0 = __expf(e0 - mx); e1 = __expf(e1 - mx);
    e2 = __expf(e2 - mx); e3 = __expf(e3 - mx);
    e4 = __expf(e4 - mx); e5 = __expf(e5 - mx);
    e6 = __expf(e6 - mx); e7 = __expf(e7 - mx);
    float s = ((e0 + e1) + (e2 + e3)) + ((e4 + e5) + (e6 + e7));

    unsigned hp2 = h * P2;
    const float4* ftp = (const float4*)feature_table;
    float ax = 0.f, ay = 0.f, az = 0.f, aw = 0.f;
    float ej[8] = {e0, e1, e2, e3, e4, e5, e6, e7};
#pragma unroll
    for (unsigned j = 0; j < 8; ++j) {
        unsigned a = ((j * P1) ^ hp2) & FEAT_MASK;
        float4 ft = ftp[a];
        ax = fmaf(ft.x, ej[j], ax);
        ay = fmaf(ft.y, ej[j], ay);
        az = fmaf(ft.z, ej[j], az);
        aw = fmaf(ft.w, ej[j], aw);
    }

    float scale = w / s;
    ax *= scale; ay *= scale; az *= scale; aw *= scale;

#pragma unroll
    for (int m = 1; m < 8; m <<= 1) {
        ax += __shfl_xor(ax, m);
        ay += __shfl_xor(ay, m);
        az += __shfl_xor(az, m);
        aw += __shfl_xor(aw, m);
    }
    if (corner == 0) {
        ((float4*)out)[p] = make_float4(ax, ay, az, aw);
    }
}

extern "C" void kernel_launch(void* const* d_in, const int* in_sizes, int n_in,
                              void* d_out, int out_size, void* d_ws, size_t ws_size,
                              hipStream_t stream) {
    const float* x  = (const float*)d_in[0];
    const float* ft = (const float*)d_in[1];
    const float* it = (const float*)d_in[2];

    const size_t F_BYTES = (size_t)IDX_SIZE * 8u;   // 4 MiB (bf16x4 rows)

    if (ws_size >= F_BYTES) {
        u2v* F = (u2v*)d_ws;
        // Phase 1: 2^20 y-lanes = 4096 blocks of 256
        hipLaunchKernelGGL(build_F_y, dim3((1u << 20) / 256), dim3(256), 0, stream,
                           (const f4v*)ft, it, F);
        // Phase 2: 250K lanes, 2 points each
        const int lanes2 = NPOINTS / 2;
        hipLaunchKernelGGL(interp2, dim3((lanes2 + 255) / 256), dim3(256), 0, stream,
                           x, F, (float4*)d_out);
    } else {
        const int total = NPOINTS * 8;
        hipLaunchKernelGGL(hashgrid_fwd, dim3((total + 255) / 256), dim3(256), 0, stream,
                           x, ft, it, (float*)d_out);
    }
}